// Round 9
// baseline (1717.121 us; speedup 1.0000x reference)
//
#include <hip/hip_runtime.h>

#define IMG 1024

constexpr int TW = 104;          // output cols per block = 4 groups x 26
constexpr int TH = 60;           // output rows per block (12 waves x CH)
constexpr int CH = 5;            // rows per wave
constexpr int GW = 118, GH = 74, GWH = 59;   // guide tile, de-interleaved halves
constexpr int XW = 112, XH = 68, XWH = 56;   // blended tile, de-interleaved halves

typedef float v2f __attribute__((ext_vector_type(2)));

__device__ __forceinline__ int refl(int i) {
  i = (i < 0) ? -i : i;
  return (i >= IMG) ? (2 * IMG - 2 - i) : i;
}
// de-interleaved column slot within a row: evens first, odds at +half
__device__ __forceinline__ int gcolr(int c) { return ((c & 1) ? GWH : 0) + (c >> 1); }
__device__ __forceinline__ int xcolr(int c) { return ((c & 1) ? XWH : 0) + (c >> 1); }

template <int CTRL>
__device__ __forceinline__ float dpp_shl(float x) {
  int r = __builtin_amdgcn_update_dpp(0, __builtin_bit_cast(int, x), CTRL, 0xF, 0xF, true);
  return __builtin_bit_cast(float, r);
}

// raw v_exp_f32: safe here (arg <= 0; denormal result flushes to 0 == desired w)
__device__ __forceinline__ float fexp2(float x) {
#if __has_builtin(__builtin_amdgcn_exp2f)
  return __builtin_amdgcn_exp2f(x);
#else
  return exp2f(x);
#endif
}

template <bool XB, bool YB>
__device__ __forceinline__ void nlm_body(
    const float* __restrict__ Gs, const float* __restrict__ XBs,
    float* __restrict__ Out, size_t ib, int tx0, int ty0, float hv) {
  const int lane = threadIdx.x;
  const int g = lane >> 4, li = lane & 15;   // 16-lane group, index in group
  const int hx = 13 * g + li;                // de-interleaved half-col base
  const int c0 = 26 * g + 2 * li;            // ext col base (even); also output block-col
  const int wv = threadIdx.y;                // 0..11
  const int cy0 = ty0 + wv * CH;
  const int rb0row = wv * CH + 4;

  // border-only tables
  int lryW[CH + 6];
  if constexpr (YB) {
#pragma unroll
    for (int j = 0; j < CH + 6; ++j)
      lryW[j] = (refl(cy0 - 3 + j) - (ty0 - 7)) * GW;
  }
  int lc0, lc1;
  if constexpr (XB) {
    lc0 = refl(tx0 - 3 + c0) - (tx0 - 7);
    lc1 = refl(tx0 - 2 + c0) - (tx0 - 7);
  }

  // center guide values (staging applied reflection -> affine always)
  v2f Gc[CH + 6];
#pragma unroll
  for (int j = 0; j < CH + 6; ++j) {
    int rw = (rb0row + j) * GW + hx + 2;
    v2f t; t.x = Gs[rw]; t.y = Gs[rw + GWH];
    Gc[j] = t;
  }

  // per-pixel exp2 coefficient from Laplacian of blended xb
  v2f cfo[CH], num[CH], den[CH];
#pragma unroll
  for (int r = 0; r < CH; ++r) {
    int rw = (rb0row + r) * XW + hx;
    float cen0 = XBs[rw + 2];                 // col c0+4 (even half)
    float cen1 = XBs[rw + XWH + 2];           // col c0+5 (odd half)
    float lap0 = XBs[rw - XW + 2] + XBs[rw + XW + 2] +
                 XBs[rw + XWH + 1] + cen1 - 4.0f * cen0;   // left=c0+3 (odd)
    float lap1 = XBs[rw - XW + XWH + 2] + XBs[rw + XW + XWH + 2] +
                 cen0 + XBs[rw + 3] - 4.0f * cen1;         // right=c0+6 (even)
    float sg0 = hv * lap0, sg1 = hv * lap1;
    cfo[r].x = -0.029442756956917622f / (sg0 * sg0 + 1e-8f);  // -log2(e)/49 / s2
    cfo[r].y = -0.029442756956917622f / (sg1 * sg1 + 1e-8f);
    num[r] = (v2f)0.0f;
    den[r] = (v2f)0.0f;
  }

#pragma unroll 1
  for (int dy = 0; dy < 9; ++dy) {
    const int gdy = (dy - 4) * GW;
    const int grb = (rb0row + dy - 4) * GW;
    const int xrb = (rb0row + dy - 4) * XW + hx;
#pragma unroll 1
    for (int dx = 0; dx < 9; ++dx) {
      int gc0, gc1;
      if constexpr (XB) {
        gc0 = gcolr(lc0 + dx - 4);
        gc1 = gcolr(lc1 + dx - 4);
      } else {
        gc0 = ((dx & 1) ? GWH : 0) + hx + (dx >> 1);
        gc1 = ((dx & 1) ? 0 : GWH) + hx + ((dx + 1) >> 1);
      }
      const int xc0 = ((dx & 1) ? XWH : 0) + (dx >> 1);        // hx folded into xrb
      const int xc1 = ((dx & 1) ? 0 : XWH) + ((dx + 1) >> 1);
      v2f er[6], V = (v2f)0.0f;
#pragma unroll
      for (int j = 0; j < 6; ++j) {
        const int rw = YB ? (lryW[j] + gdy) : (grb + j * GW);
        v2f gs; gs.x = Gs[rw + gc0]; gs.y = Gs[rw + gc1];
        v2f d = Gc[j] - gs;
        er[j] = d;
        V = __builtin_elementwise_fma(d, d, V);
      }
#pragma unroll
      for (int r = 0; r < CH; ++r) {
        const int rw = YB ? (lryW[r + 6] + gdy) : (grb + (r + 6) * GW);
        v2f gs; gs.x = Gs[rw + gc0]; gs.y = Gs[rw + gc1];
        v2f d = Gc[r + 6] - gs;
        V = __builtin_elementwise_fma(d, d, V);
        // horizontal 7-tap via DPP row-shifts (within 16-lane group)
        float P = V.x + V.y;
        float Q = P + dpp_shl<0x101>(P);
        float T = Q + dpp_shl<0x102>(Q);
        float S0 = T - dpp_shl<0x103>(V.y);
        float S1 = T - V.x;
        v2f Sv; Sv.x = S0; Sv.y = S1;
        Sv *= cfo[r];                          // packed mul
        v2f w; w.x = fexp2(Sv.x); w.y = fexp2(Sv.y);
        const int xr = xrb + r * XW;
        v2f xv; xv.x = XBs[xr + xc0]; xv.y = XBs[xr + xc1];
        num[r] = __builtin_elementwise_fma(w, xv, num[r]);
        den[r] += w;
        v2f o = er[r];                          // r < 6: pure ring
        V = __builtin_elementwise_fma(-o, o, V);
        er[r] = d;
      }
    }
  }

  if (li <= 12) {
    const int px0 = tx0 + c0;
#pragma unroll
    for (int r = 0; r < CH; ++r) {
      size_t o = ib + (size_t)(cy0 + r) * IMG + px0;
      v2f res = num[r] / den[r];
      *reinterpret_cast<v2f*>(Out + o) = res;   // px0 even -> 8B aligned
    }
  }
}

__global__ __launch_bounds__(768, 6) void nlm_kernel(
    const float* __restrict__ Y, const float* __restrict__ Xp,
    float* __restrict__ Out,
    const float* __restrict__ Harr, int hidx,
    const float* __restrict__ Sarr, int sidx) {
  __shared__ float Gs[GH * GW];
  __shared__ float XBs[XH * XW];

  const int b = blockIdx.z;
  // overlap-clamp last blocks so reflected reads stay inside staged tiles
  int ty0 = blockIdx.y * TH;
  if (ty0 > IMG - TH) ty0 = IMG - TH;
  int tx0 = blockIdx.x * TW;
  if (tx0 > IMG - TW) tx0 = IMG - TW;
  const int gy0 = ty0 - 7, gx0 = tx0 - 7;
  const int xy0 = ty0 - 4, xx0 = tx0 - 4;

  const float hv = Harr[hidx];
  float stepv = 1.0f;
  if (sidx >= 0) stepv = fminf(fmaxf(Sarr[sidx], 0.6f), 1.0f);
  const float omst = 1.0f - stepv;

  const size_t ib = (size_t)b * (IMG * IMG);
  const float* __restrict__ Yb = Y + ib;
  const float* __restrict__ Xb = Xp + ib;

  const int tid = threadIdx.y * 64 + threadIdx.x;

  // stage guide tile, de-interleaved (reflection applied at staging)
  for (int i = tid; i < GH * GW; i += 768) {
    int u = i / GW, v = i - u * GW;
    Gs[u * GW + gcolr(v)] = Yb[refl(gy0 + u) * IMG + refl(gx0 + v)];
  }
  // stage blended noisy tile xb = (1-step)*x_prev + step*y, de-interleaved
  for (int i = tid; i < XH * XW; i += 768) {
    int u = i / XW, v = i - u * XW;
    int gidx = refl(xy0 + u) * IMG + refl(xx0 + v);
    XBs[u * XW + xcolr(v)] = omst * Xb[gidx] + stepv * Yb[gidx];
  }
  __syncthreads();

  // border if the guide-tile footprint leaves the image
  const bool xb = (tx0 < 7) || (tx0 + TW + 7 > IMG);
  const bool yb = (ty0 < 7) || (ty0 + TH + 7 > IMG);
  if (!xb && !yb)      nlm_body<false, false>(Gs, XBs, Out, ib, tx0, ty0, hv);
  else if (!xb)        nlm_body<false, true >(Gs, XBs, Out, ib, tx0, ty0, hv);
  else if (!yb)        nlm_body<true,  false>(Gs, XBs, Out, ib, tx0, ty0, hv);
  else                 nlm_body<true,  true >(Gs, XBs, Out, ib, tx0, ty0, hv);
}

extern "C" void kernel_launch(void* const* d_in, const int* in_sizes, int n_in,
                              void* d_out, int out_size, void* d_ws, size_t ws_size,
                              hipStream_t stream) {
  const float* Y = (const float*)d_in[0];
  const float* Harr = (const float*)d_in[1];
  const float* Sarr = (const float*)d_in[2];
  float* Out = (float*)d_out;
  float* Ws = (float*)d_ws;

  const int B = in_sizes[0] / (IMG * IMG);
  dim3 block(64, 12, 1);
  dim3 grid((IMG + TW - 1) / TW, (IMG + TH - 1) / TH, B);

  nlm_kernel<<<grid, block, 0, stream>>>(Y, Y, Ws, Harr, 0, Sarr, -1);
  nlm_kernel<<<grid, block, 0, stream>>>(Y, Ws, Out, Harr, 1, Sarr, 0);
  nlm_kernel<<<grid, block, 0, stream>>>(Y, Out, Ws, Harr, 2, Sarr, 1);
  nlm_kernel<<<grid, block, 0, stream>>>(Y, Ws, Out, Harr, 3, Sarr, 2);
}

// Round 11
// 1159.418 us; speedup vs baseline: 1.4810x; 1.4810x over previous
//
#include <hip/hip_runtime.h>

#define IMG 1024

constexpr int TW = 104;          // output cols per block = 4 groups x 26
constexpr int TH = 40;           // output rows per block (8 waves x CH)
constexpr int CH = 5;            // rows per wave
constexpr int GW = 118, GH = 54, GWH = 59;   // guide tile, de-interleaved halves
constexpr int XW = 112, XH = 48, XWH = 56;   // blended tile, de-interleaved halves

typedef float v2f __attribute__((ext_vector_type(2)));

__device__ __forceinline__ int refl(int i) {
  i = (i < 0) ? -i : i;
  return (i >= IMG) ? (2 * IMG - 2 - i) : i;
}
__device__ __forceinline__ int gcolr(int c) { return ((c & 1) ? GWH : 0) + (c >> 1); }
__device__ __forceinline__ int xcolr(int c) { return ((c & 1) ? XWH : 0) + (c >> 1); }

template <int CTRL>
__device__ __forceinline__ float dpp_shl(float x) {
  int r = __builtin_amdgcn_update_dpp(0, __builtin_bit_cast(int, x), CTRL, 0xF, 0xF, true);
  return __builtin_bit_cast(float, r);
}

// raw v_exp_f32: safe here (arg <= 0; denormal result flushes to 0 == desired w)
__device__ __forceinline__ float fexp2(float x) {
#if __has_builtin(__builtin_amdgcn_exp2f)
  return __builtin_amdgcn_exp2f(x);
#else
  return exp2f(x);
#endif
}

template <bool XB, bool YB>
__device__ __forceinline__ void nlm_body(
    const float* __restrict__ Gs, const float* __restrict__ XBs,
    float* __restrict__ Out, size_t ib, int tx0, int ty0, float hv) {
  const int lane = threadIdx.x;
  const int g = lane >> 4, li = lane & 15;   // 16-lane group, index in group
  const int hx = 13 * g + li;                // de-interleaved half-col base (G reads)
  const int hxc = (hx > 51) ? 51 : hx;       // clamped for X-tile (halo lanes: dead data)
  const int c0 = 26 * g + 2 * li;            // ext col base (even)
  const int wv = threadIdx.y;                // 0..7
  const int cy0 = ty0 + wv * CH;
  const int rb0row = wv * CH + 4;

  // border-only column indices
  int lc0, lc1;
  if constexpr (XB) {
    lc0 = refl(tx0 - 3 + c0) - (tx0 - 7);
    lc1 = refl(tx0 - 2 + c0) - (tx0 - 7);
  }
  // y-border-only row table: Gs row of R(p_y); window offset added affinely later
  int lryW[CH + 6];
  if constexpr (YB) {
#pragma unroll
    for (int j = 0; j < CH + 6; ++j)
      lryW[j] = (refl(cy0 - 3 + j) - (ty0 - 7)) * GW;
  }

  // center guide values (staging applied reflection -> affine always)
  v2f Gc[CH + 6];
#pragma unroll
  for (int j = 0; j < CH + 6; ++j) {
    int rw = (rb0row + j) * GW + hx + 2;
    v2f t; t.x = Gs[rw]; t.y = Gs[rw + GWH];
    Gc[j] = t;
  }

  // per-pixel exp2 coefficient from Laplacian of blended xb
  v2f cfo[CH], num[CH], den[CH];
#pragma unroll
  for (int r = 0; r < CH; ++r) {
    int rw = (rb0row + r) * XW + hxc;
    float cen0 = XBs[rw + 2];
    float cen1 = XBs[rw + XWH + 2];
    float lap0 = XBs[rw - XW + 2] + XBs[rw + XW + 2] +
                 XBs[rw + XWH + 1] + cen1 - 4.0f * cen0;
    float lap1 = XBs[rw - XW + XWH + 2] + XBs[rw + XW + XWH + 2] +
                 cen0 + XBs[rw + 3] - 4.0f * cen1;
    float sg0 = hv * lap0, sg1 = hv * lap1;
    cfo[r].x = -0.029442756956917622f / (sg0 * sg0 + 1e-8f);  // -log2(e)/49 / s2
    cfo[r].y = -0.029442756956917622f / (sg1 * sg1 + 1e-8f);
    num[r] = (v2f)0.0f;
    den[r] = (v2f)0.0f;
  }

#pragma unroll 1
  for (int dx = 0; dx < 9; ++dx) {
    int gc0, gc1;
    if constexpr (XB) {
      gc0 = gcolr(lc0 + dx - 4);
      gc1 = gcolr(lc1 + dx - 4);
    } else {
      gc0 = ((dx & 1) ? GWH : 0) + hx + (dx >> 1);
      gc1 = ((dx & 1) ? 0 : GWH) + hx + ((dx + 1) >> 1);
    }
    const int xc0 = ((dx & 1) ? XWH : 0) + (dx >> 1) + hxc;
    const int xc1 = ((dx & 1) ? 0 : XWH) + ((dx + 1) >> 1) + hxc;

    if constexpr (!YB) {
      // interior rows: register-cache the shifted guide column (affine, exact)
      v2f Greg[CH + 14];
#pragma unroll
      for (int k = 0; k < CH + 14; ++k) {
        const int rw = (wv * CH + k) * GW;
        v2f t; t.x = Gs[rw + gc0]; t.y = Gs[rw + gc1];
        Greg[k] = t;
      }
#pragma unroll
      for (int dy = 0; dy < 9; ++dy) {
        v2f V = (v2f)0.0f;
#pragma unroll
        for (int j = 0; j < 6; ++j) {
          v2f d = Gc[j] - Greg[j + dy];
          V = __builtin_elementwise_fma(d, d, V);
        }
#pragma unroll
        for (int r = 0; r < CH; ++r) {
          v2f d = Gc[r + 6] - Greg[r + 6 + dy];
          V = __builtin_elementwise_fma(d, d, V);
          // horizontal 7-tap via DPP row-shifts (within 16-lane group)
          float P = V.x + V.y;
          float Q = P + dpp_shl<0x101>(P);
          float T = Q + dpp_shl<0x102>(Q);
          float S0 = T - dpp_shl<0x103>(V.y);
          float S1 = T - V.x;
          v2f w; w.x = fexp2(S0 * cfo[r].x); w.y = fexp2(S1 * cfo[r].y);
          const int xr = (rb0row + dy - 4 + r) * XW;
          v2f xv; xv.x = XBs[xr + xc0]; xv.y = XBs[xr + xc1];
          num[r] = __builtin_elementwise_fma(w, xv, num[r]);
          den[r] += w;
          // retire row r by recomputing its d (no ring registers)
          v2f o = Gc[r] - Greg[r + dy];
          V = __builtin_elementwise_fma(-o, o, V);
        }
      }
    } else {
      // y-border rows: two-step reflection R(R(p_y)+t_y) -> per-(dy) LDS reads
#pragma unroll 1
      for (int dy = 0; dy < 9; ++dy) {
        const int gdy = (dy - 4) * GW;
        v2f er[CH >= 6 ? CH : 6], V = (v2f)0.0f;
#pragma unroll
        for (int j = 0; j < 6; ++j) {
          const int rw = lryW[j] + gdy;
          v2f gs; gs.x = Gs[rw + gc0]; gs.y = Gs[rw + gc1];
          v2f d = Gc[j] - gs;
          er[j % (CH >= 6 ? CH : 6)] = d;
          V = __builtin_elementwise_fma(d, d, V);
        }
#pragma unroll
        for (int r = 0; r < CH; ++r) {
          const int rw = lryW[r + 6] + gdy;
          v2f gs; gs.x = Gs[rw + gc0]; gs.y = Gs[rw + gc1];
          v2f d = Gc[r + 6] - gs;
          V = __builtin_elementwise_fma(d, d, V);
          float P = V.x + V.y;
          float Q = P + dpp_shl<0x101>(P);
          float T = Q + dpp_shl<0x102>(Q);
          float S0 = T - dpp_shl<0x103>(V.y);
          float S1 = T - V.x;
          v2f w; w.x = fexp2(S0 * cfo[r].x); w.y = fexp2(S1 * cfo[r].y);
          const int xr = (rb0row + dy - 4 + r) * XW;
          v2f xv; xv.x = XBs[xr + xc0]; xv.y = XBs[xr + xc1];
          num[r] = __builtin_elementwise_fma(w, xv, num[r]);
          den[r] += w;
          v2f o = er[r % (CH >= 6 ? CH : 6)];
          V = __builtin_elementwise_fma(-o, o, V);
          er[r % (CH >= 6 ? CH : 6)] = d;
        }
      }
    }
  }

  if (li <= 12) {
    const int px0 = tx0 + c0;
#pragma unroll
    for (int r = 0; r < CH; ++r) {
      size_t o = ib + (size_t)(cy0 + r) * IMG + px0;
      v2f res = num[r] / den[r];
      *reinterpret_cast<v2f*>(Out + o) = res;   // px0 even -> 8B aligned
    }
  }
}

__global__ __launch_bounds__(512, 4) void nlm_kernel(
    const float* __restrict__ Y, const float* __restrict__ Xp,
    float* __restrict__ Out,
    const float* __restrict__ Harr, int hidx,
    const float* __restrict__ Sarr, int sidx) {
  __shared__ float Gs[GH * GW];
  __shared__ float XBs[XH * XW];

  const int b = blockIdx.z;
  // overlap-clamp last blocks so reflected reads stay inside staged tiles
  int ty0 = blockIdx.y * TH;
  if (ty0 > IMG - TH) ty0 = IMG - TH;
  int tx0 = blockIdx.x * TW;
  if (tx0 > IMG - TW) tx0 = IMG - TW;
  const int gy0 = ty0 - 7, gx0 = tx0 - 7;
  const int xy0 = ty0 - 4, xx0 = tx0 - 4;

  const float hv = Harr[hidx];
  float stepv = 1.0f;
  if (sidx >= 0) stepv = fminf(fmaxf(Sarr[sidx], 0.6f), 1.0f);
  const float omst = 1.0f - stepv;

  const size_t ib = (size_t)b * (IMG * IMG);
  const float* __restrict__ Yb = Y + ib;
  const float* __restrict__ Xb = Xp + ib;

  const int tid = threadIdx.y * 64 + threadIdx.x;

  // stage guide tile, de-interleaved (reflection applied at staging)
  for (int i = tid; i < GH * GW; i += 512) {
    int u = i / GW, v = i - u * GW;
    Gs[u * GW + gcolr(v)] = Yb[refl(gy0 + u) * IMG + refl(gx0 + v)];
  }
  // stage blended noisy tile xb = (1-step)*x_prev + step*y, de-interleaved
  for (int i = tid; i < XH * XW; i += 512) {
    int u = i / XW, v = i - u * XW;
    int gidx = refl(xy0 + u) * IMG + refl(xx0 + v);
    XBs[u * XW + xcolr(v)] = omst * Xb[gidx] + stepv * Yb[gidx];
  }
  __syncthreads();

  // border if the guide-tile footprint leaves the image
  const bool xb = (tx0 < 7) || (tx0 + TW + 7 > IMG);
  const bool yb = (ty0 < 7) || (ty0 + TH + 7 > IMG);
  if (!xb && !yb)      nlm_body<false, false>(Gs, XBs, Out, ib, tx0, ty0, hv);
  else if (!xb)        nlm_body<false, true >(Gs, XBs, Out, ib, tx0, ty0, hv);
  else if (!yb)        nlm_body<true,  false>(Gs, XBs, Out, ib, tx0, ty0, hv);
  else                 nlm_body<true,  true >(Gs, XBs, Out, ib, tx0, ty0, hv);
}

extern "C" void kernel_launch(void* const* d_in, const int* in_sizes, int n_in,
                              void* d_out, int out_size, void* d_ws, size_t ws_size,
                              hipStream_t stream) {
  const float* Y = (const float*)d_in[0];
  const float* Harr = (const float*)d_in[1];
  const float* Sarr = (const float*)d_in[2];
  float* Out = (float*)d_out;
  float* Ws = (float*)d_ws;

  const int B = in_sizes[0] / (IMG * IMG);
  dim3 block(64, 8, 1);
  dim3 grid((IMG + TW - 1) / TW, (IMG + TH - 1) / TH, B);

  nlm_kernel<<<grid, block, 0, stream>>>(Y, Y, Ws, Harr, 0, Sarr, -1);
  nlm_kernel<<<grid, block, 0, stream>>>(Y, Ws, Out, Harr, 1, Sarr, 0);
  nlm_kernel<<<grid, block, 0, stream>>>(Y, Out, Ws, Harr, 2, Sarr, 1);
  nlm_kernel<<<grid, block, 0, stream>>>(Y, Ws, Out, Harr, 3, Sarr, 2);
}